// Round 1
// baseline (3957.872 us; speedup 1.0000x reference)
//
#include <hip/hip_runtime.h>

#define NCH 16
#define HID 128
#define NB 32
#define NH 256
#define NW 256
#define HW (NH*NW)          // 65536 = 2^16
#define CHW (NCH*HW)        // 1048576 = 2^20

// ws float offsets for transposed weights
#define W1T_OFF 0           // [64][128]
#define W2T_OFF 8192        // [128][128]
#define W3T_OFF 24576       // [128][128]
#define W4T_OFF 40960       // [128][16]
#define FAC_OFF_BYTES (43008*4)

__global__ void transpose_weights_k(const float* __restrict__ w1,
                                    const float* __restrict__ w2,
                                    const float* __restrict__ w3,
                                    const float* __restrict__ w4,
                                    float* __restrict__ ws) {
  int i = blockIdx.x * 256 + threadIdx.x;
  if (i < 8192)  { int c = i >> 7, o = i & 127; ws[W1T_OFF + i] = w1[o*64 + c]; }
  if (i < 16384) { int c = i >> 7, o = i & 127; ws[W2T_OFF + i] = w2[o*128 + c];
                                                ws[W3T_OFF + i] = w3[o*128 + c]; }
  if (i < 2048)  { int c = i >> 4, o = i & 15; ws[W4T_OFF + i] = w4[o*128 + c]; }
}

// Fused: perception conv -> 3x lrelu matvec -> dy -> x_new = x + dy*mask
// block = 256 threads (4 waves), tile = 1 row x 64 cols.
// Wave w computes output channels [32w, 32w+32) for all 64 pixels.
__global__ __launch_bounds__(256, 2)
void nca_mlp_k(const float* __restrict__ x,
               const float* __restrict__ ws,
               const float* __restrict__ b1,
               const float* __restrict__ b2,
               const float* __restrict__ b3,
               const float* __restrict__ mask,
               float* __restrict__ xn) {
  __shared__ float bufA[HID][64];   // 32 KB
  __shared__ float bufB[HID][64];   // 32 KB

  const int tid = threadIdx.x;
  const int px  = tid & 63;
  const int wv  = tid >> 6;
  const int col = blockIdx.x * 64 + px;
  const int row = blockIdx.y;
  const int b   = blockIdx.z;

  // ---- perception: y[64 ch][64 px] -> bufA[0..63] ----
  for (int ch = wv; ch < NCH; ch += 4) {
    const float* xp = x + (size_t)b * CHW + (size_t)ch * HW;
    float v[3][3];
#pragma unroll
    for (int dy = 0; dy < 3; ++dy) {
#pragma unroll
      for (int dx = 0; dx < 3; ++dx) {
        int yy = row + dy - 1, xx = col + dx - 1;
        v[dy][dx] = (yy >= 0 && yy < NH && xx >= 0 && xx < NW) ? xp[yy * NW + xx] : 0.0f;
      }
    }
    float fid = v[1][1];
    float fsx = -v[0][0] + v[0][2] - 2.f*v[1][0] + 2.f*v[1][2] - v[2][0] + v[2][2];
    float fsy = -v[0][0] - 2.f*v[0][1] - v[0][2] + v[2][0] + 2.f*v[2][1] + v[2][2];
    float flap = v[0][0]+v[0][1]+v[0][2]+v[1][0]-8.f*v[1][1]+v[1][2]+v[2][0]+v[2][1]+v[2][2];
    bufA[ch*4+0][px] = fid;
    bufA[ch*4+1][px] = fsx;
    bufA[ch*4+2][px] = fsy;
    bufA[ch*4+3][px] = flap;
  }
  __syncthreads();

  // ---- layer 1: bufA(y,K=64) -> bufB(h1) ----
  {
    const int o0 = __builtin_amdgcn_readfirstlane(wv * 32);
    const float* wt = ws + W1T_OFF;
    float acc[32];
#pragma unroll
    for (int i = 0; i < 32; ++i) acc[i] = 0.f;
#pragma unroll 1
    for (int c = 0; c < 64; ++c) {
      float v = bufA[c][px];
      const float* wr = wt + c * 128 + o0;
#pragma unroll
      for (int i = 0; i < 32; ++i) acc[i] = fmaf(wr[i], v, acc[i]);
    }
#pragma unroll
    for (int i = 0; i < 32; ++i) {
      float t = acc[i] + b1[o0 + i];
      bufB[o0 + i][px] = (t > 0.f) ? t : 0.01f * t;
    }
  }
  __syncthreads();

  // ---- layer 2: bufB(h1,K=128) -> bufA(h2) ----
  {
    const int o0 = __builtin_amdgcn_readfirstlane(wv * 32);
    const float* wt = ws + W2T_OFF;
    float acc[32];
#pragma unroll
    for (int i = 0; i < 32; ++i) acc[i] = 0.f;
#pragma unroll 1
    for (int c = 0; c < 128; ++c) {
      float v = bufB[c][px];
      const float* wr = wt + c * 128 + o0;
#pragma unroll
      for (int i = 0; i < 32; ++i) acc[i] = fmaf(wr[i], v, acc[i]);
    }
#pragma unroll
    for (int i = 0; i < 32; ++i) {
      float t = acc[i] + b2[o0 + i];
      bufA[o0 + i][px] = (t > 0.f) ? t : 0.01f * t;
    }
  }
  __syncthreads();

  // ---- layer 3: bufA(h2,K=128) -> bufB(h3) ----
  {
    const int o0 = __builtin_amdgcn_readfirstlane(wv * 32);
    const float* wt = ws + W3T_OFF;
    float acc[32];
#pragma unroll
    for (int i = 0; i < 32; ++i) acc[i] = 0.f;
#pragma unroll 1
    for (int c = 0; c < 128; ++c) {
      float v = bufA[c][px];
      const float* wr = wt + c * 128 + o0;
#pragma unroll
      for (int i = 0; i < 32; ++i) acc[i] = fmaf(wr[i], v, acc[i]);
    }
#pragma unroll
    for (int i = 0; i < 32; ++i) {
      float t = acc[i] + b3[o0 + i];
      bufB[o0 + i][px] = (t > 0.f) ? t : 0.01f * t;
    }
  }
  __syncthreads();

  // ---- layer 4: bufB(h3,K=128) -> dy(16) -> bufA[0..15] ----
  {
    const int o0 = __builtin_amdgcn_readfirstlane(wv * 4);
    const float* wt = ws + W4T_OFF;
    float acc[4] = {0.f, 0.f, 0.f, 0.f};
#pragma unroll 1
    for (int c = 0; c < 128; ++c) {
      float v = bufB[c][px];
      const float* wr = wt + c * 16 + o0;
#pragma unroll
      for (int i = 0; i < 4; ++i) acc[i] = fmaf(wr[i], v, acc[i]);
    }
#pragma unroll
    for (int i = 0; i < 4; ++i) bufA[o0 + i][px] = acc[i];
  }
  __syncthreads();

  // ---- update: x_new = x + dy * mask ----
  {
    const float m = mask[(size_t)b * HW + row * NW + col];
    for (int ch = wv; ch < NCH; ch += 4) {
      size_t idx = (size_t)b * CHW + (size_t)ch * HW + row * NW + col;
      xn[idx] = x[idx] + bufA[ch][px] * m;
    }
  }
}

// factor = pre_alive(x) * post_alive(x_new), per pixel, as bytes
__global__ void alive_factor_k(const float* __restrict__ x,
                               const float* __restrict__ xn,
                               unsigned char* __restrict__ fac) {
  const int col = threadIdx.x;
  const int row = blockIdx.y;
  const int b   = blockIdx.z;
  const float NEG = -3.4e38f;
  float m0 = NEG, m1 = NEG, n0 = NEG, n1 = NEG;
  const size_t base0 = (size_t)b * CHW;
  const size_t base1 = base0 + HW;
#pragma unroll
  for (int dy = -1; dy <= 1; ++dy) {
    int yy = row + dy;
    if (yy < 0 || yy >= NH) continue;
#pragma unroll
    for (int dx = -1; dx <= 1; ++dx) {
      int xx = col + dx;
      if (xx < 0 || xx >= NW) continue;
      int off = yy * NW + xx;
      m0 = fmaxf(m0, x[base0 + off]);
      m1 = fmaxf(m1, x[base1 + off]);
      n0 = fmaxf(n0, xn[base0 + off]);
      n1 = fmaxf(n1, xn[base1 + off]);
    }
  }
  bool pre  = (fabsf(m0) + fabsf(m1)) > 0.01f;
  bool post = (fabsf(n0) + fabsf(n1)) > 0.01f;
  fac[(size_t)b * HW + row * NW + col] = (pre && post) ? 1 : 0;
}

// out *= factor (in place, float4)
__global__ void scale_k(float* __restrict__ xn, const unsigned char* __restrict__ fac) {
  unsigned int i4 = blockIdx.x * 256 + threadIdx.x;
  unsigned int e = i4 * 4;
  unsigned int b = e >> 20;          // CHW = 2^20
  unsigned int pix = e & (HW - 1);   // HW = 2^16
  float4 v = ((const float4*)xn)[i4];
  const unsigned char* f = fac + ((size_t)b << 16) + pix;
  v.x *= (float)f[0];
  v.y *= (float)f[1];
  v.z *= (float)f[2];
  v.w *= (float)f[3];
  ((float4*)xn)[i4] = v;
}

extern "C" void kernel_launch(void* const* d_in, const int* in_sizes, int n_in,
                              void* d_out, int out_size, void* d_ws, size_t ws_size,
                              hipStream_t stream) {
  const float* x    = (const float*)d_in[0];
  const float* w1   = (const float*)d_in[1];
  const float* b1   = (const float*)d_in[2];
  const float* w2   = (const float*)d_in[3];
  const float* b2   = (const float*)d_in[4];
  const float* w3   = (const float*)d_in[5];
  const float* b3   = (const float*)d_in[6];
  const float* w4   = (const float*)d_in[7];
  const float* mask = (const float*)d_in[8];
  // d_in[9] = steps, fixed at 1 by setup_inputs

  float* ws_f = (float*)d_ws;
  unsigned char* fac = (unsigned char*)d_ws + FAC_OFF_BYTES;
  float* xn = (float*)d_out;

  transpose_weights_k<<<64, 256, 0, stream>>>(w1, w2, w3, w4, ws_f);
  dim3 gA(NW / 64, NH, NB);
  nca_mlp_k<<<gA, 256, 0, stream>>>(x, ws_f, b1, b2, b3, mask, xn);
  dim3 gB(1, NH, NB);
  alive_factor_k<<<gB, 256, 0, stream>>>(x, xn, fac);
  scale_k<<<(NB * CHW) / (256 * 4), 256, 0, stream>>>(xn, fac);
}

// Round 2
// 394.797 us; speedup vs baseline: 10.0251x; 10.0251x over previous
//
#include <hip/hip_runtime.h>

typedef _Float16 f16;
typedef f16 f16x2 __attribute__((ext_vector_type(2)));
typedef f16 f16x8 __attribute__((ext_vector_type(8)));
typedef float f32x4 __attribute__((ext_vector_type(4)));
typedef float f32x16 __attribute__((ext_vector_type(16)));

#define NCH 16
#define NB 32
#define NH 256
#define NW 256
#define HW (NH*NW)
#define CHW (NCH*HW)

// ws layout in f16 elements (A-fragment order for MFMA)
#define WF1_OFF 0        // [4 ob][4 kt][64 lane][8j] = 8192   (w1: 128x64)
#define WF2_OFF 8192     // [4 ob][8 kt][64][8]      = 16384  (w2: 128x128)
#define WF3_OFF 24576    // [4 ob][8 kt][64][8]      = 16384  (w3: 128x128)
#define WF4_OFF 40960    // [4 kt][64][8]            = 2048   (w4: 16x128)

// A-frag layouts:
//  32x32x16: A[m][k], m = lane&31, k = (lane>>5)*8 + j
//  16x16x32: A[m][k], m = lane&15, k = (lane>>4)*8 + j
__global__ void prep_wfrag_k(const float* __restrict__ w1, const float* __restrict__ w2,
                             const float* __restrict__ w3, const float* __restrict__ w4,
                             f16* __restrict__ wf) {
  int id = blockIdx.x * 256 + threadIdx.x;   // grid covers 43008
  if (id < 8192) {
    int j = id & 7, l = (id >> 3) & 63, kt = (id >> 9) & 3, ob = id >> 11;
    int o = ob * 32 + (l & 31), c = kt * 16 + (l >> 5) * 8 + j;
    wf[WF1_OFF + id] = (f16)w1[o * 64 + c];
  } else if (id < 24576) {
    int t = id - 8192;
    int j = t & 7, l = (t >> 3) & 63, kt = (t >> 9) & 7, ob = t >> 12;
    int o = ob * 32 + (l & 31), c = kt * 16 + (l >> 5) * 8 + j;
    wf[WF2_OFF + t] = (f16)w2[o * 128 + c];
  } else if (id < 40960) {
    int t = id - 24576;
    int j = t & 7, l = (t >> 3) & 63, kt = (t >> 9) & 7, ob = t >> 12;
    int o = ob * 32 + (l & 31), c = kt * 16 + (l >> 5) * 8 + j;
    wf[WF3_OFF + t] = (f16)w3[o * 128 + c];
  } else if (id < 43008) {
    int t = id - 40960;
    int j = t & 7, l = (t >> 3) & 63, kt = t >> 9;
    int o = l & 15, c = kt * 32 + (l >> 4) * 8 + j;
    wf[WF4_OFF + t] = (f16)w4[o * 128 + c];
  }
}

// LDS activation layout: act[p][c] fp16, row = 256 B, byte = p*256 + ((c*2) ^ ((p&15)<<4))
#define ABYTE(p, c) ((p) * 256 + (((c) * 2) ^ (((p) & 15) << 4)))

// One GEMM layer on 32x32x16 MFMA: out[128][64px] = lrelu(W[128][K] * in[K][64] + b)
template <int K>
__device__ __forceinline__ void layer32(const unsigned char* sin, unsigned char* sout,
                                        const f16* __restrict__ wfL,
                                        const float* __restrict__ bias,
                                        int wv, int lane) {
  constexpr int NKT = K / 16;
  f16x8 af[NKT];
  const f16x8* wp = (const f16x8*)wfL + (size_t)wv * NKT * 64 + lane;
#pragma unroll
  for (int kt = 0; kt < NKT; ++kt) af[kt] = wp[kt * 64];

  const int o0 = wv * 32;
  float bv[16];
#pragma unroll
  for (int r = 0; r < 16; ++r) {
    int m = (r & 3) + 8 * (r >> 2) + 4 * (lane >> 5);
    bv[r] = bias[o0 + m];
  }
  f32x16 acc[2];
#pragma unroll
  for (int pt = 0; pt < 2; ++pt)
#pragma unroll
    for (int r = 0; r < 16; ++r) acc[pt][r] = bv[r];

#pragma unroll
  for (int kt = 0; kt < NKT; ++kt) {
#pragma unroll
    for (int pt = 0; pt < 2; ++pt) {
      int p = pt * 32 + (lane & 31);
      int c0 = kt * 16 + (lane >> 5) * 8;
      f16x8 bf = *(const f16x8*)(sin + ABYTE(p, c0));
      acc[pt] = __builtin_amdgcn_mfma_f32_32x32x16_f16(af[kt], bf, acc[pt], 0, 0, 0);
    }
  }

#pragma unroll
  for (int pt = 0; pt < 2; ++pt) {
    int p = pt * 32 + (lane & 31);
#pragma unroll
    for (int r = 0; r < 16; r += 2) {
      float v0 = acc[pt][r], v1 = acc[pt][r + 1];
      v0 = v0 > 0.f ? v0 : 0.01f * v0;
      v1 = v1 > 0.f ? v1 : 0.01f * v1;
      int m = (r & 3) + 8 * (r >> 2) + 4 * (lane >> 5);  // even r -> even m, m+1 for r+1
      int o = o0 + m;
      f16x2 pr = {(f16)v0, (f16)v1};
      *(f16x2*)(sout + ABYTE(p, o)) = pr;
    }
  }
}

__global__ __launch_bounds__(256, 4)
void nca_mlp_k(const float* __restrict__ x, const f16* __restrict__ wf,
               const float* __restrict__ b1, const float* __restrict__ b2,
               const float* __restrict__ b3, const float* __restrict__ mask,
               float* __restrict__ xn) {
  __shared__ unsigned char smA[16384];
  __shared__ unsigned char smB[16384];
  const int tid = threadIdx.x;
  const int lane = tid & 63;
  const int wv = tid >> 6;
  const int col0 = blockIdx.x * 64;
  const int row = blockIdx.y;
  const int b = blockIdx.z;

  // ---- perception conv (fp32) -> act1 fp16 in smA, c = 4*ch + {id,sx,sy,lap} ----
  {
    const int px = lane;
    const int col = col0 + px;
    for (int ch = wv; ch < NCH; ch += 4) {
      const float* xp = x + (size_t)b * CHW + (size_t)ch * HW;
      float v[3][3];
#pragma unroll
      for (int dy = 0; dy < 3; ++dy) {
#pragma unroll
        for (int dx = 0; dx < 3; ++dx) {
          int yy = row + dy - 1, xx = col + dx - 1;
          v[dy][dx] = (yy >= 0 && yy < NH && xx >= 0 && xx < NW) ? xp[yy * NW + xx] : 0.0f;
        }
      }
      float fid = v[1][1];
      float fsx = -v[0][0] + v[0][2] - 2.f * v[1][0] + 2.f * v[1][2] - v[2][0] + v[2][2];
      float fsy = -v[0][0] - 2.f * v[0][1] - v[0][2] + v[2][0] + 2.f * v[2][1] + v[2][2];
      float flap = v[0][0] + v[0][1] + v[0][2] + v[1][0] - 8.f * v[1][1] + v[1][2] +
                   v[2][0] + v[2][1] + v[2][2];
      int c = ch * 4;
      f16x2 p01 = {(f16)fid, (f16)fsx};
      f16x2 p23 = {(f16)fsy, (f16)flap};
      *(f16x2*)(smA + ABYTE(px, c)) = p01;
      *(f16x2*)(smA + ABYTE(px, c + 2)) = p23;
    }
  }
  __syncthreads();

  layer32<64>(smA, smB, wf + WF1_OFF, b1, wv, lane);   // act1 -> h1
  __syncthreads();
  layer32<128>(smB, smA, wf + WF2_OFF, b2, wv, lane);  // h1 -> h2
  __syncthreads();
  layer32<128>(smA, smB, wf + WF3_OFF, b3, wv, lane);  // h2 -> h3
  __syncthreads();

  // ---- layer 4 (16x16x32): dy[16][64px], wave wv owns p-tile wv ----
  {
    f16x8 a4[4];
    const f16x8* wp4 = (const f16x8*)(wf + WF4_OFF) + lane;
#pragma unroll
    for (int kt = 0; kt < 4; ++kt) a4[kt] = wp4[kt * 64];
    f32x4 acc;
#pragma unroll
    for (int r = 0; r < 4; ++r) acc[r] = 0.f;
    const int p = wv * 16 + (lane & 15);
#pragma unroll
    for (int kt = 0; kt < 4; ++kt) {
      int c0 = kt * 32 + (lane >> 4) * 8;
      f16x8 bf = *(const f16x8*)(smB + ABYTE(p, c0));
      acc = __builtin_amdgcn_mfma_f32_16x16x32_f16(a4[kt], bf, acc, 0, 0, 0);
    }
    float* dyb = (float*)smA;  // [16][65] f32, reuse smA
#pragma unroll
    for (int r = 0; r < 4; ++r) {
      int o = (lane >> 4) * 4 + r;
      dyb[o * 65 + p] = acc[r];
    }
  }
  __syncthreads();

  // ---- update: x_new = x + dy * mask ----
  {
    const int px = lane;
    const int col = col0 + px;
    const float m = mask[(size_t)b * HW + row * NW + col];
    const float* dyb = (const float*)smA;
    for (int ch = wv; ch < NCH; ch += 4) {
      size_t idx = (size_t)b * CHW + (size_t)ch * HW + row * NW + col;
      xn[idx] = x[idx] + dyb[ch * 65 + px] * m;
    }
  }
}

// fac = pre_alive(x) * post_alive(xn); zero all 16 channels where dead
__global__ void alive_scale_k(const float* __restrict__ x, float* __restrict__ xn) {
  const int col = threadIdx.x;
  const int row = blockIdx.x;
  const int b = blockIdx.y;
  const float NEG = -3.4e38f;
  float m0 = NEG, m1 = NEG, n0 = NEG, n1 = NEG;
  const size_t base0 = (size_t)b * CHW;
  const size_t base1 = base0 + HW;
#pragma unroll
  for (int dy = -1; dy <= 1; ++dy) {
    int yy = row + dy;
    if (yy < 0 || yy >= NH) continue;
#pragma unroll
    for (int dx = -1; dx <= 1; ++dx) {
      int xx = col + dx;
      if (xx < 0 || xx >= NW) continue;
      int off = yy * NW + xx;
      m0 = fmaxf(m0, x[base0 + off]);
      m1 = fmaxf(m1, x[base1 + off]);
      n0 = fmaxf(n0, xn[base0 + off]);
      n1 = fmaxf(n1, xn[base1 + off]);
    }
  }
  bool alive = ((fabsf(m0) + fabsf(m1)) > 0.01f) && ((fabsf(n0) + fabsf(n1)) > 0.01f);
  if (!alive) {
    size_t pix = base0 + row * NW + col;
#pragma unroll
    for (int ch = 0; ch < NCH; ++ch) xn[pix + (size_t)ch * HW] = 0.f;
  }
}

extern "C" void kernel_launch(void* const* d_in, const int* in_sizes, int n_in,
                              void* d_out, int out_size, void* d_ws, size_t ws_size,
                              hipStream_t stream) {
  const float* x    = (const float*)d_in[0];
  const float* w1   = (const float*)d_in[1];
  const float* b1   = (const float*)d_in[2];
  const float* w2   = (const float*)d_in[3];
  const float* b2   = (const float*)d_in[4];
  const float* w3   = (const float*)d_in[5];
  const float* b3   = (const float*)d_in[6];
  const float* w4   = (const float*)d_in[7];
  const float* mask = (const float*)d_in[8];

  f16* wf = (f16*)d_ws;
  float* xn = (float*)d_out;

  prep_wfrag_k<<<168, 256, 0, stream>>>(w1, w2, w3, w4, wf);
  nca_mlp_k<<<dim3(NW / 64, NH, NB), 256, 0, stream>>>(x, wf, b1, b2, b3, mask, xn);
  alive_scale_k<<<dim3(NH, NB), 256, 0, stream>>>(x, xn);
}